// Round 1
// baseline (251.993 us; speedup 1.0000x reference)
//
#include <hip/hip_runtime.h>

// ---------------------------------------------------------------------------
// IntraAgg: neighbor top-S + train-pos top-P aggregation + concat + GEMM+ReLU
// B=8192, K=64 (S=33), Ppool=2048 (P=33), D=128, Dout=128. All f32.
// ws layout: [cat: B*2D f32][sorted pool vals: Ppool f32][sorted pool gidx: Ppool i32]
// ---------------------------------------------------------------------------

// Kernel 0: rank-sort the train-pos pool by logit-0 value (exact, deterministic).
__global__ __launch_bounds__(256) void sort_pool_kernel(
    const float* __restrict__ tp_logits,   // [Ppool][2]
    const int*   __restrict__ tp_idx,      // [Ppool]
    float* __restrict__ sv,                // out: sorted values [Ppool]
    int*   __restrict__ sg,                // out: feature row idx in sorted order
    int Ppool)
{
    __shared__ float v[2048];
    int t = threadIdx.x;
    for (int j = t; j < Ppool && j < 2048; j += blockDim.x) v[j] = tp_logits[2 * j];
    __syncthreads();
    int i = blockIdx.x * blockDim.x + t;
    if (i < Ppool) {
        float vi = v[i];
        int r = 0;
        for (int j = 0; j < Ppool; ++j) {
            float vj = v[j];
            r += (vj < vi) || (vj == vi && j < i);   // total order -> distinct ranks
        }
        sv[r] = vi;
        sg[r] = tp_idx[i];
    }
}

// Kernel 1: per-row selection + gather-sum; writes cat[b] = [feat(center), agg].
__global__ __launch_bounds__(256) void row_kernel(
    const float* __restrict__ features,     // [N][D]
    const float* __restrict__ all_logits,   // [N][2]
    const float* __restrict__ center_logits,// [B][2]
    const int*   __restrict__ center_idx,   // [B]
    const int*   __restrict__ neighbor_idx, // [B][K]
    const int*   __restrict__ labels,       // [B]
    const int*   __restrict__ avgp,         // [1]
    const float* __restrict__ sv,           // [Ppool] sorted pool values
    const int*   __restrict__ sg,           // [Ppool] pool feature idx (sorted order)
    float* __restrict__ cat,                // [B][2D]
    int K, int S, int Ppool, int D)
{
    __shared__ float svl[2048];
    __shared__ float dnb[256];
    __shared__ int   nbi[256];
    __shared__ float wd[512];
    __shared__ int   sel[512];     // [0,S): neighbor nodes; [S,S+P): pos nodes
    __shared__ float red2[256];
    __shared__ int   lo_s;

    const int b = blockIdx.x;
    const int t = threadIdx.x;
    const float c0 = center_logits[2 * b];

    // --- neighbor distances + exact stable rank-select (top_k semantics) ---
    if (t < K) {
        int nb = neighbor_idx[(size_t)b * K + t];
        nbi[t] = nb;
        dnb[t] = fabsf(all_logits[2 * nb] - c0);
    }
    __syncthreads();
    if (t < K) {
        float dv = dnb[t];
        int r = 0;
        for (int j = 0; j < K; ++j) {
            float dj = dnb[j];
            r += (dj < dv) || (dj == dv && j < t);
        }
        if (r < S) sel[r] = nbi[t];
    }

    const int isPos = (labels[b] == 1);
    const int P = isPos ? (avgp[0] + 1) : 0;

    if (isPos) {
        // stage sorted pool values (L2-hot, coalesced)
        const float* svp;
        if (Ppool <= 2048) {
            for (int j = t; j < Ppool; j += blockDim.x) svl[j] = sv[j];
            svp = svl;
        } else {
            svp = sv;
        }
        __syncthreads();
        if (t == 0) {
            int lo = 0, hi = Ppool;
            while (lo < hi) {
                int mid = (lo + hi) >> 1;
                if (svp[mid] < c0) lo = mid + 1; else hi = mid;
            }
            lo_s = lo;
        }
        __syncthreads();
        const int lo = lo_s;
        int w0 = lo - P; if (w0 < 0) w0 = 0;
        int w1 = lo + P; if (w1 > Ppool) w1 = Ppool;
        const int wsz = w1 - w0;     // <= 2P, contains the P closest (window property)
        for (int i = t; i < wsz; i += blockDim.x) wd[i] = fabsf(svp[w0 + i] - c0);
        __syncthreads();
        for (int i = t; i < wsz; i += blockDim.x) {
            float dv = wd[i];
            int r = 0;
            for (int j = 0; j < wsz; ++j) {
                float dj = wd[j];
                r += (dj < dv) || (dj == dv && j < i);
            }
            if (r < P) sel[S + r] = sg[w0 + i];
        }
    }
    __syncthreads();

    // --- gather-sum features of selected nodes ---
    const int total = S + P;
    const int parts = blockDim.x / D;      // 2 for D=128
    const int part  = t / D;
    const int d     = t - part * D;
    float acc = 0.f;
    for (int i = part; i < total; i += parts)
        acc += features[(size_t)sel[i] * D + d];
    red2[t] = acc;
    __syncthreads();
    if (part == 0) {
        float s = acc;
        for (int p = 1; p < parts; ++p) s += red2[p * D + d];
        float agg = s / (float)total;
        size_t cb = (size_t)b * (2 * D);
        cat[cb + d]     = features[(size_t)center_idx[b] * D + d];
        cat[cb + D + d] = agg;
    }
}

// Kernel 2: out = relu(cat @ W^T + b).  M x Kd @ (128 x Kd)^T -> M x 128.
// 32-row x 128-col tile per block, K-chunks of 64 staged in LDS (W transposed).
__global__ __launch_bounds__(256) void gemm_relu_kernel(
    const float* __restrict__ A,    // [M][Kd]
    const float* __restrict__ W,    // [128][Kd]
    const float* __restrict__ bias, // [128]
    float* __restrict__ out,        // [M][128]
    int M, int Kd)
{
    __shared__ __align__(16) float As[32][68];    // pad 68: bank spread + 16B rows
    __shared__ __align__(16) float Ws[64][132];   // W^T tile [k][o], pad 132
    const int t  = threadIdx.x;
    const int m0 = blockIdx.x * 32;
    const int cg = t & 31;    // col group: cols cg*4..+3
    const int rg = t >> 5;    // row group: rows rg*4..+3
    float acc[4][4] = {};

    for (int kc = 0; kc < Kd; kc += 64) {
        // stage A tile (32 x 64), 2 float4 per thread, coalesced
        for (int e = t; e < 512; e += 256) {
            int r = e >> 4, c4 = (e & 15) * 4;
            float4 val = make_float4(0.f, 0.f, 0.f, 0.f);
            int m = m0 + r;
            if (m < M) val = *(const float4*)&A[(size_t)m * Kd + kc + c4];
            *(float4*)&As[r][c4] = val;
        }
        // stage W^T tile (64 x 128): read along k (coalesced), scatter-transpose
        for (int e = t; e < 2048; e += 256) {
            int o = e >> 4, k4 = (e & 15) * 4;
            float4 wv = *(const float4*)&W[(size_t)o * Kd + kc + k4];
            Ws[k4 + 0][o] = wv.x;
            Ws[k4 + 1][o] = wv.y;
            Ws[k4 + 2][o] = wv.z;
            Ws[k4 + 3][o] = wv.w;
        }
        __syncthreads();

        for (int k4 = 0; k4 < 64; k4 += 4) {
            float4 a[4], w[4];
#pragma unroll
            for (int i = 0; i < 4; ++i) a[i] = *(const float4*)&As[rg * 4 + i][k4];
#pragma unroll
            for (int kk = 0; kk < 4; ++kk) w[kk] = *(const float4*)&Ws[k4 + kk][cg * 4];
#pragma unroll
            for (int kk = 0; kk < 4; ++kk) {
#pragma unroll
                for (int i = 0; i < 4; ++i) {
                    float av = ((const float*)&a[i])[kk];
                    acc[i][0] = fmaf(av, w[kk].x, acc[i][0]);
                    acc[i][1] = fmaf(av, w[kk].y, acc[i][1]);
                    acc[i][2] = fmaf(av, w[kk].z, acc[i][2]);
                    acc[i][3] = fmaf(av, w[kk].w, acc[i][3]);
                }
            }
        }
        __syncthreads();
    }

    float4 bv = *(const float4*)&bias[cg * 4];
#pragma unroll
    for (int i = 0; i < 4; ++i) {
        int m = m0 + rg * 4 + i;
        if (m < M) {
            float4 o;
            o.x = fmaxf(acc[i][0] + bv.x, 0.f);
            o.y = fmaxf(acc[i][1] + bv.y, 0.f);
            o.z = fmaxf(acc[i][2] + bv.z, 0.f);
            o.w = fmaxf(acc[i][3] + bv.w, 0.f);
            *(float4*)&out[(size_t)m * 128 + cg * 4] = o;
        }
    }
}

extern "C" void kernel_launch(void* const* d_in, const int* in_sizes, int n_in,
                              void* d_out, int out_size, void* d_ws, size_t ws_size,
                              hipStream_t stream) {
    const float* features      = (const float*)d_in[0];
    const float* all_logits    = (const float*)d_in[1];
    const float* center_logits = (const float*)d_in[2];
    const float* tp_logits     = (const float*)d_in[3];
    const float* W             = (const float*)d_in[4];
    const float* bias          = (const float*)d_in[5];
    const int*   center_idx    = (const int*)d_in[6];
    const int*   neighbor_idx  = (const int*)d_in[7];
    const int*   tp_idx        = (const int*)d_in[8];
    const int*   labels        = (const int*)d_in[9];
    const int*   avgp          = (const int*)d_in[10];

    const int B     = in_sizes[6];
    const int K     = in_sizes[7] / B;
    const int S     = K / 2 + 1;
    const int Ppool = in_sizes[8];
    const int Dout  = in_sizes[5];
    const int D     = in_sizes[4] / (2 * Dout);

    char* ws = (char*)d_ws;
    float* cat  = (float*)ws;                                   // B * 2D f32
    size_t cat_bytes = (size_t)B * 2 * D * sizeof(float);
    float* sv_g = (float*)(ws + cat_bytes);                     // Ppool f32
    int*   sg_g = (int*)(ws + cat_bytes + (size_t)Ppool * 4);   // Ppool i32

    sort_pool_kernel<<<(Ppool + 255) / 256, 256, 0, stream>>>(
        tp_logits, tp_idx, sv_g, sg_g, Ppool);

    row_kernel<<<B, 256, 0, stream>>>(
        features, all_logits, center_logits, center_idx, neighbor_idx,
        labels, avgp, sv_g, sg_g, cat, K, S, Ppool, D);

    gemm_relu_kernel<<<(B + 31) / 32, 256, 0, stream>>>(
        cat, W, bias, (float*)d_out, B, 2 * D);
}

// Round 3
// 226.663 us; speedup vs baseline: 1.1118x; 1.1118x over previous
//
#include <hip/hip_runtime.h>

// ---------------------------------------------------------------------------
// IntraAgg: neighbor top-S + train-pos top-P aggregation + concat + GEMM+ReLU
// B=8192, K=64 (S=33), Ppool=2048 (P=33), D=128, Dout=128. All f32.
// ws layout: [cat: B*2D f32][sorted pool vals: Ppool f32][sorted pool gidx: Ppool i32]
// ---------------------------------------------------------------------------

// Kernel 0: rank-sort the train-pos pool by logit-0 value (exact, deterministic).
// v2: float4 LDS reads + unroll -> pipelined instead of 2048 dependent ds_reads.
__global__ __launch_bounds__(256) void sort_pool_kernel(
    const float* __restrict__ tp_logits,   // [Ppool][2]
    const int*   __restrict__ tp_idx,      // [Ppool]
    float* __restrict__ sv,                // out: sorted values [Ppool]
    int*   __restrict__ sg,                // out: feature row idx in sorted order
    int Ppool)
{
    __shared__ float v[2048];
    const int t = threadIdx.x;
    for (int j = t; j < Ppool; j += 256) v[j] = tp_logits[2 * j];
    __syncthreads();
    const int i = blockIdx.x * 256 + t;
    if (i >= Ppool) return;
    const float vi = v[i];
    const float4* v4 = (const float4*)v;
    const int P4 = Ppool >> 2;
    int r = 0;
#pragma unroll 8
    for (int j4 = 0; j4 < P4; ++j4) {
        float4 x = v4[j4];
        int j = j4 * 4;
        r += (x.x < vi) || (x.x == vi && (j + 0) < i);
        r += (x.y < vi) || (x.y == vi && (j + 1) < i);
        r += (x.z < vi) || (x.z == vi && (j + 2) < i);
        r += (x.w < vi) || (x.w == vi && (j + 3) < i);
    }
    for (int j = P4 << 2; j < Ppool; ++j) {
        float vj = v[j];
        r += (vj < vi) || (vj == vi && j < i);
    }
    sv[r] = vi;
    sg[r] = tp_idx[i];
}

// Kernel 1 v2: per-row selection + float4 gather-sum; cat[b] = [feat(center), agg].
// - no LDS pool staging: binary search + window read directly on global sv (L1/L2-hot)
// - gather: 8 rows in flight x 32 lanes x float4 (512B per half-wave, coalesced)
__global__ __launch_bounds__(256) void row_kernel(
    const float* __restrict__ features,     // [N][D]
    const float* __restrict__ all_logits,   // [N][2]
    const float* __restrict__ center_logits,// [B][2]
    const int*   __restrict__ center_idx,   // [B]
    const int*   __restrict__ neighbor_idx, // [B][K]
    const int*   __restrict__ labels,       // [B]
    const int*   __restrict__ avgp,         // [1]
    const float* __restrict__ sv,           // [Ppool] sorted pool values
    const int*   __restrict__ sg,           // [Ppool] pool feature idx (sorted order)
    float* __restrict__ cat,                // [B][2D]
    int K, int S, int Ppool, int D)
{
    __shared__ float dnb[64];
    __shared__ int   nbi[64];
    __shared__ float wd[96];
    __shared__ int   sel[96];      // [0,S): neighbor nodes; [S,S+P): pos nodes
    __shared__ float4 red4[8][32];
    __shared__ int   lo_s;

    const int b = blockIdx.x;
    const int t = threadIdx.x;
    const float c0 = center_logits[2 * b];

    // --- neighbor distances + exact stable rank-select (top_k semantics) ---
    if (t < K) {
        int nb = neighbor_idx[(size_t)b * K + t];
        nbi[t] = nb;
        dnb[t] = fabsf(all_logits[2 * nb] - c0);
    }
    const int isPos = (labels[b] == 1);           // block-uniform
    const int P = isPos ? (avgp[0] + 1) : 0;
    __syncthreads();
    if (t < K) {
        float dv = dnb[t];
        int r = 0;
#pragma unroll 8
        for (int j = 0; j < K; ++j) {
            float dj = dnb[j];
            r += (dj < dv) || (dj == dv && j < t);
        }
        if (r < S) sel[r] = nbi[t];
    }

    if (isPos) {
        if (t == 0) {
            int lo = 0, hi = Ppool;
            while (lo < hi) {
                int mid = (lo + hi) >> 1;
                if (sv[mid] < c0) lo = mid + 1; else hi = mid;
            }
            lo_s = lo;
        }
        __syncthreads();
        const int lo = lo_s;
        int w0 = lo - P; if (w0 < 0) w0 = 0;
        int w1 = lo + P; if (w1 > Ppool) w1 = Ppool;
        const int wsz = w1 - w0;   // <= 2P; contains the P closest (window property)
        if (t < wsz) wd[t] = fabsf(sv[w0 + t] - c0);
        __syncthreads();
        if (t < wsz) {
            float dv = wd[t];
            int r = 0;
#pragma unroll 4
            for (int j = 0; j < wsz; ++j) {
                float dj = wd[j];
                r += (dj < dv) || (dj == dv && j < t);
            }
            if (r < P) sel[S + r] = sg[w0 + t];
        }
    }
    __syncthreads();

    // --- float4 gather-sum: 8 rows in flight, 32 lanes per row ---
    const int total = S + P;
    const int nf4 = D >> 2;                 // 32 for D=128
    const int g   = t / nf4;                // 8 row groups
    const int c   = t - g * nf4;
    const int ng  = blockDim.x / nf4;       // 8
    const float4* f4 = (const float4*)features;
    float4 acc = make_float4(0.f, 0.f, 0.f, 0.f);
    for (int i = g; i < total; i += ng) {
        float4 x = f4[(size_t)sel[i] * nf4 + c];
        acc.x += x.x; acc.y += x.y; acc.z += x.z; acc.w += x.w;
    }
    red4[g][c] = acc;
    __syncthreads();
    if (g < 4) {
        float4 a = red4[g][c], o = red4[g + 4][c];
        a.x += o.x; a.y += o.y; a.z += o.z; a.w += o.w;
        red4[g][c] = a;
    }
    __syncthreads();
    if (g < 2) {
        float4 a = red4[g][c], o = red4[g + 2][c];
        a.x += o.x; a.y += o.y; a.z += o.z; a.w += o.w;
        red4[g][c] = a;
    }
    __syncthreads();
    float4* cat4 = (float4*)cat;
    const size_t cb4 = (size_t)b * ((2 * D) >> 2);
    if (g == 0) {
        float4 a = red4[0][c], o = red4[1][c];
        float inv = 1.f / (float)total;
        float4 w;
        w.x = (a.x + o.x) * inv; w.y = (a.y + o.y) * inv;
        w.z = (a.z + o.z) * inv; w.w = (a.w + o.w) * inv;
        cat4[cb4 + nf4 + c] = w;
    } else if (g == 1) {
        cat4[cb4 + c] = f4[(size_t)center_idx[b] * nf4 + c];
    }
}

// Kernel 2: out = relu(cat @ W^T + b).  M x Kd @ (128 x Kd)^T -> M x 128.
// 32-row x 128-col tile per block, K-chunks of 64 staged in LDS (W transposed).
__global__ __launch_bounds__(256) void gemm_relu_kernel(
    const float* __restrict__ A,    // [M][Kd]
    const float* __restrict__ W,    // [128][Kd]
    const float* __restrict__ bias, // [128]
    float* __restrict__ out,        // [M][128]
    int M, int Kd)
{
    __shared__ __align__(16) float As[32][68];    // pad 68: bank spread + 16B rows
    __shared__ __align__(16) float Ws[64][132];   // W^T tile [k][o], pad 132
    const int t  = threadIdx.x;
    const int m0 = blockIdx.x * 32;
    const int cg = t & 31;    // col group: cols cg*4..+3
    const int rg = t >> 5;    // row group: rows rg*4..+3
    float acc[4][4] = {};

    for (int kc = 0; kc < Kd; kc += 64) {
        // stage A tile (32 x 64), 2 float4 per thread, coalesced
        for (int e = t; e < 512; e += 256) {
            int r = e >> 4, c4 = (e & 15) * 4;
            float4 val = make_float4(0.f, 0.f, 0.f, 0.f);
            int m = m0 + r;
            if (m < M) val = *(const float4*)&A[(size_t)m * Kd + kc + c4];
            *(float4*)&As[r][c4] = val;
        }
        // stage W^T tile (64 x 128): read along k (coalesced), scatter-transpose
        for (int e = t; e < 2048; e += 256) {
            int o = e >> 4, k4 = (e & 15) * 4;
            float4 wv = *(const float4*)&W[(size_t)o * Kd + kc + k4];
            Ws[k4 + 0][o] = wv.x;
            Ws[k4 + 1][o] = wv.y;
            Ws[k4 + 2][o] = wv.z;
            Ws[k4 + 3][o] = wv.w;
        }
        __syncthreads();

        for (int k4 = 0; k4 < 64; k4 += 4) {
            float4 a[4], w[4];
#pragma unroll
            for (int i = 0; i < 4; ++i) a[i] = *(const float4*)&As[rg * 4 + i][k4];
#pragma unroll
            for (int kk = 0; kk < 4; ++kk) w[kk] = *(const float4*)&Ws[k4 + kk][cg * 4];
#pragma unroll
            for (int kk = 0; kk < 4; ++kk) {
#pragma unroll
                for (int i = 0; i < 4; ++i) {
                    float av = ((const float*)&a[i])[kk];
                    acc[i][0] = fmaf(av, w[kk].x, acc[i][0]);
                    acc[i][1] = fmaf(av, w[kk].y, acc[i][1]);
                    acc[i][2] = fmaf(av, w[kk].z, acc[i][2]);
                    acc[i][3] = fmaf(av, w[kk].w, acc[i][3]);
                }
            }
        }
        __syncthreads();
    }

    float4 bv = *(const float4*)&bias[cg * 4];
#pragma unroll
    for (int i = 0; i < 4; ++i) {
        int m = m0 + rg * 4 + i;
        if (m < M) {
            float4 o;
            o.x = fmaxf(acc[i][0] + bv.x, 0.f);
            o.y = fmaxf(acc[i][1] + bv.y, 0.f);
            o.z = fmaxf(acc[i][2] + bv.z, 0.f);
            o.w = fmaxf(acc[i][3] + bv.w, 0.f);
            *(float4*)&out[(size_t)m * 128 + cg * 4] = o;
        }
    }
}

extern "C" void kernel_launch(void* const* d_in, const int* in_sizes, int n_in,
                              void* d_out, int out_size, void* d_ws, size_t ws_size,
                              hipStream_t stream) {
    const float* features      = (const float*)d_in[0];
    const float* all_logits    = (const float*)d_in[1];
    const float* center_logits = (const float*)d_in[2];
    const float* tp_logits     = (const float*)d_in[3];
    const float* W             = (const float*)d_in[4];
    const float* bias          = (const float*)d_in[5];
    const int*   center_idx    = (const int*)d_in[6];
    const int*   neighbor_idx  = (const int*)d_in[7];
    const int*   tp_idx        = (const int*)d_in[8];
    const int*   labels        = (const int*)d_in[9];
    const int*   avgp          = (const int*)d_in[10];

    const int B     = in_sizes[6];
    const int K     = in_sizes[7] / B;
    const int S     = K / 2 + 1;
    const int Ppool = in_sizes[8];
    const int Dout  = in_sizes[5];
    const int D     = in_sizes[4] / (2 * Dout);

    char* ws = (char*)d_ws;
    float* cat  = (float*)ws;                                   // B * 2D f32
    size_t cat_bytes = (size_t)B * 2 * D * sizeof(float);
    float* sv_g = (float*)(ws + cat_bytes);                     // Ppool f32
    int*   sg_g = (int*)(ws + cat_bytes + (size_t)Ppool * 4);   // Ppool i32

    sort_pool_kernel<<<(Ppool + 255) / 256, 256, 0, stream>>>(
        tp_logits, tp_idx, sv_g, sg_g, Ppool);

    row_kernel<<<B, 256, 0, stream>>>(
        features, all_logits, center_logits, center_idx, neighbor_idx,
        labels, avgp, sv_g, sg_g, cat, K, S, Ppool, D);

    gemm_relu_kernel<<<(B + 31) / 32, 256, 0, stream>>>(
        cat, W, bias, (float*)d_out, B, 2 * D);
}

// Round 4
// 164.411 us; speedup vs baseline: 1.5327x; 1.3786x over previous
//
#include <hip/hip_runtime.h>

// ---------------------------------------------------------------------------
// IntraAgg: neighbor top-S + train-pos top-P aggregation + concat + GEMM+ReLU
// B=8192, K=64 (S=33), Ppool=2048 (P=33), D=128, Dout=128. All f32.
// ws layout: [cat: B*2D f32][sorted pool vals: Ppool f32][sorted pool gidx: Ppool i32]
// ---------------------------------------------------------------------------

// Kernel 0 v3: parallel rank-sort, one WAVE per pool element (512 blocks).
// v2 failure: 8 blocks -> 0.33% occupancy, 59us. Now comparisons/thread 2048->32.
__global__ __launch_bounds__(256) void sort_pool_kernel(
    const float* __restrict__ tp_logits,   // [Ppool][2]
    const int*   __restrict__ tp_idx,      // [Ppool]
    float* __restrict__ sv,                // out: sorted values [Ppool]
    int*   __restrict__ sg,                // out: feature row idx in sorted order
    int Ppool)
{
    __shared__ float v[2048];
    const int t = threadIdx.x;
    const float2* tp2 = (const float2*)tp_logits;
    const bool useL = (Ppool <= 2048);
    if (useL) {
        for (int j = t; j < Ppool; j += 256) v[j] = tp2[j].x;
        __syncthreads();
    }
    const int lane = t & 63;
    const int i = blockIdx.x * 4 + (t >> 6);
    if (i >= Ppool) return;
    const float vi = useL ? v[i] : tp2[i].x;
    int r = 0;
    for (int j = lane; j < Ppool; j += 64) {
        float vj = useL ? v[j] : tp2[j].x;
        r += (int)((vj < vi) | ((vj == vi) & (j < i)));   // total order -> distinct ranks
    }
#pragma unroll
    for (int off = 32; off > 0; off >>= 1) r += __shfl_down(r, off);
    if (lane == 0) { sv[r] = vi; sg[r] = tp_idx[i]; }
}

// Kernel 1 v3: wave-specialized phase 1, parallel pool-count (no serial binary
// search), deep-batched gather loads. Assumes blockDim=256, K<=64, S+P<=96.
__global__ __launch_bounds__(256) void row_kernel(
    const float* __restrict__ features,     // [N][D]
    const float* __restrict__ all_logits,   // [N][2]
    const float* __restrict__ center_logits,// [B][2]
    const int*   __restrict__ center_idx,   // [B]
    const int*   __restrict__ neighbor_idx, // [B][K]
    const int*   __restrict__ labels,       // [B]
    const int*   __restrict__ avgp,         // [1]
    const float* __restrict__ sv,           // [Ppool] sorted pool values
    const int*   __restrict__ sg,           // [Ppool] pool feature idx (sorted order)
    float* __restrict__ cat,                // [B][2D]
    int K, int S, int Ppool, int D)
{
    __shared__ int    sel[96];     // [0,S): neighbor nodes; [S,S+P): pos nodes
    __shared__ float  wd[96];
    __shared__ float4 red4[4][32];
    __shared__ int    lo_s;

    const int b    = blockIdx.x;
    const int t    = threadIdx.x;
    const int lane = t & 63;
    const int wave = t >> 6;
    const float c0 = center_logits[2 * b];
    const int isPos = (labels[b] == 1);            // block-uniform
    const int P = isPos ? (avgp[0] + 1) : 0;
    const int nf4 = D >> 2;                        // 32 for D=128
    const float4* f4 = (const float4*)features;
    float4* cat4 = (float4*)cat;
    const size_t cb4 = (size_t)b * (size_t)(2 * nf4);

    // ---- phase 1: independent per-wave work, no barriers ----
    if (wave == 0) {
        // neighbor distance + exact stable rank (top_k tie-break) via shfl
        float dv = 3.4e38f;
        int nb = 0;
        if (lane < K) {
            nb = neighbor_idx[(size_t)b * K + lane];
            dv = fabsf(all_logits[2 * nb] - c0);
        }
        int r = 0;
#pragma unroll
        for (int j = 0; j < 64; ++j) {
            float dj = __shfl(dv, j);
            r += (int)((dj < dv) | ((dj == dv) & (j < lane)));
        }
        if (lane < K && r < S) sel[r] = nb;
    } else if (wave == 1) {
        if (isPos) {
            // lo = #{j : sv[j] < c0}  (== lower_bound), wave-parallel
            int cnt = 0;
            for (int j = lane; j < Ppool; j += 64) cnt += (int)(sv[j] < c0);
#pragma unroll
            for (int off = 32; off > 0; off >>= 1) cnt += __shfl_down(cnt, off);
            if (lane == 0) lo_s = cnt;
        }
    } else if (wave == 2) {
        if (lane < nf4)
            cat4[cb4 + lane] = f4[(size_t)center_idx[b] * nf4 + lane];
    }
    __syncthreads();

    // ---- phase 2: window distances + rank-select (isPos only) ----
    int w0 = 0, wsz = 0;
    if (isPos) {
        const int lo = lo_s;
        w0 = lo - P; if (w0 < 0) w0 = 0;
        int w1 = lo + P; if (w1 > Ppool) w1 = Ppool;
        wsz = w1 - w0;            // <= 2P; contains the P closest (window property)
        if (t < wsz) wd[t] = fabsf(sv[w0 + t] - c0);
    }
    __syncthreads();
    if (isPos && t < wsz) {
        float dvi = wd[t];
        int r = 0;
#pragma unroll 8
        for (int j = 0; j < wsz; ++j) {
            float dj = wd[j];
            r += (int)((dj < dvi) | ((dj == dvi) & (j < t)));
        }
        if (r < P) sel[S + r] = sg[w0 + t];
    }
    __syncthreads();

    // ---- phase 3: gather-sum, 8 groups x 32 lanes, deep-batched loads ----
    const int total = S + P;       // 33 or 66
    const int g = t >> 5, c = t & 31;
    float4 acc = make_float4(0.f, 0.f, 0.f, 0.f);
    int i = g;
    if (i + 56 < total) {          // 8-deep batch (8 loads in flight)
        float4 x0 = f4[(size_t)sel[i     ] * nf4 + c];
        float4 x1 = f4[(size_t)sel[i +  8] * nf4 + c];
        float4 x2 = f4[(size_t)sel[i + 16] * nf4 + c];
        float4 x3 = f4[(size_t)sel[i + 24] * nf4 + c];
        float4 x4 = f4[(size_t)sel[i + 32] * nf4 + c];
        float4 x5 = f4[(size_t)sel[i + 40] * nf4 + c];
        float4 x6 = f4[(size_t)sel[i + 48] * nf4 + c];
        float4 x7 = f4[(size_t)sel[i + 56] * nf4 + c];
        acc.x = ((x0.x + x1.x) + (x2.x + x3.x)) + ((x4.x + x5.x) + (x6.x + x7.x));
        acc.y = ((x0.y + x1.y) + (x2.y + x3.y)) + ((x4.y + x5.y) + (x6.y + x7.y));
        acc.z = ((x0.z + x1.z) + (x2.z + x3.z)) + ((x4.z + x5.z) + (x6.z + x7.z));
        acc.w = ((x0.w + x1.w) + (x2.w + x3.w)) + ((x4.w + x5.w) + (x6.w + x7.w));
        i += 64;
    }
    if (i + 24 < total) {          // 4-deep batch
        float4 x0 = f4[(size_t)sel[i     ] * nf4 + c];
        float4 x1 = f4[(size_t)sel[i +  8] * nf4 + c];
        float4 x2 = f4[(size_t)sel[i + 16] * nf4 + c];
        float4 x3 = f4[(size_t)sel[i + 24] * nf4 + c];
        acc.x += (x0.x + x1.x) + (x2.x + x3.x);
        acc.y += (x0.y + x1.y) + (x2.y + x3.y);
        acc.z += (x0.z + x1.z) + (x2.z + x3.z);
        acc.w += (x0.w + x1.w) + (x2.w + x3.w);
        i += 32;
    }
    if (i + 8 < total) {           // 2-deep batch
        float4 x0 = f4[(size_t)sel[i    ] * nf4 + c];
        float4 x1 = f4[(size_t)sel[i + 8] * nf4 + c];
        acc.x += x0.x + x1.x; acc.y += x0.y + x1.y;
        acc.z += x0.z + x1.z; acc.w += x0.w + x1.w;
        i += 16;
    }
    for (; i < total; i += 8) {
        float4 x = f4[(size_t)sel[i] * nf4 + c];
        acc.x += x.x; acc.y += x.y; acc.z += x.z; acc.w += x.w;
    }

    // ---- reduce 8 groups -> 1: shfl_xor(32) within wave, then 4-way LDS ----
    float4 o;
    o.x = __shfl_xor(acc.x, 32); o.y = __shfl_xor(acc.y, 32);
    o.z = __shfl_xor(acc.z, 32); o.w = __shfl_xor(acc.w, 32);
    acc.x += o.x; acc.y += o.y; acc.z += o.z; acc.w += o.w;
    if (lane < 32) red4[wave][c] = acc;
    __syncthreads();
    if (t < 32) {
        float4 a0 = red4[0][t], a1 = red4[1][t], a2 = red4[2][t], a3 = red4[3][t];
        float inv = 1.f / (float)total;
        float4 w;
        w.x = (a0.x + a1.x + a2.x + a3.x) * inv;
        w.y = (a0.y + a1.y + a2.y + a3.y) * inv;
        w.z = (a0.z + a1.z + a2.z + a3.z) * inv;
        w.w = (a0.w + a1.w + a2.w + a3.w) * inv;
        cat4[cb4 + nf4 + t] = w;
    }
}

// Kernel 2 (unchanged this round — not yet measured in top-5):
// out = relu(cat @ W^T + b).  M x Kd @ (128 x Kd)^T -> M x 128.
__global__ __launch_bounds__(256) void gemm_relu_kernel(
    const float* __restrict__ A,    // [M][Kd]
    const float* __restrict__ W,    // [128][Kd]
    const float* __restrict__ bias, // [128]
    float* __restrict__ out,        // [M][128]
    int M, int Kd)
{
    __shared__ __align__(16) float As[32][68];
    __shared__ __align__(16) float Ws[64][132];
    const int t  = threadIdx.x;
    const int m0 = blockIdx.x * 32;
    const int cg = t & 31;
    const int rg = t >> 5;
    float acc[4][4] = {};

    for (int kc = 0; kc < Kd; kc += 64) {
        for (int e = t; e < 512; e += 256) {
            int r = e >> 4, c4 = (e & 15) * 4;
            float4 val = make_float4(0.f, 0.f, 0.f, 0.f);
            int m = m0 + r;
            if (m < M) val = *(const float4*)&A[(size_t)m * Kd + kc + c4];
            *(float4*)&As[r][c4] = val;
        }
        for (int e = t; e < 2048; e += 256) {
            int o = e >> 4, k4 = (e & 15) * 4;
            float4 wv = *(const float4*)&W[(size_t)o * Kd + kc + k4];
            Ws[k4 + 0][o] = wv.x;
            Ws[k4 + 1][o] = wv.y;
            Ws[k4 + 2][o] = wv.z;
            Ws[k4 + 3][o] = wv.w;
        }
        __syncthreads();

        for (int k4 = 0; k4 < 64; k4 += 4) {
            float4 a[4], w[4];
#pragma unroll
            for (int i = 0; i < 4; ++i) a[i] = *(const float4*)&As[rg * 4 + i][k4];
#pragma unroll
            for (int kk = 0; kk < 4; ++kk) w[kk] = *(const float4*)&Ws[k4 + kk][cg * 4];
#pragma unroll
            for (int kk = 0; kk < 4; ++kk) {
#pragma unroll
                for (int i = 0; i < 4; ++i) {
                    float av = ((const float*)&a[i])[kk];
                    acc[i][0] = fmaf(av, w[kk].x, acc[i][0]);
                    acc[i][1] = fmaf(av, w[kk].y, acc[i][1]);
                    acc[i][2] = fmaf(av, w[kk].z, acc[i][2]);
                    acc[i][3] = fmaf(av, w[kk].w, acc[i][3]);
                }
            }
        }
        __syncthreads();
    }

    float4 bv = *(const float4*)&bias[cg * 4];
#pragma unroll
    for (int i = 0; i < 4; ++i) {
        int m = m0 + rg * 4 + i;
        if (m < M) {
            float4 o;
            o.x = fmaxf(acc[i][0] + bv.x, 0.f);
            o.y = fmaxf(acc[i][1] + bv.y, 0.f);
            o.z = fmaxf(acc[i][2] + bv.z, 0.f);
            o.w = fmaxf(acc[i][3] + bv.w, 0.f);
            *(float4*)&out[(size_t)m * 128 + cg * 4] = o;
        }
    }
}

extern "C" void kernel_launch(void* const* d_in, const int* in_sizes, int n_in,
                              void* d_out, int out_size, void* d_ws, size_t ws_size,
                              hipStream_t stream) {
    const float* features      = (const float*)d_in[0];
    const float* all_logits    = (const float*)d_in[1];
    const float* center_logits = (const float*)d_in[2];
    const float* tp_logits     = (const float*)d_in[3];
    const float* W             = (const float*)d_in[4];
    const float* bias          = (const float*)d_in[5];
    const int*   center_idx    = (const int*)d_in[6];
    const int*   neighbor_idx  = (const int*)d_in[7];
    const int*   tp_idx        = (const int*)d_in[8];
    const int*   labels        = (const int*)d_in[9];
    const int*   avgp          = (const int*)d_in[10];

    const int B     = in_sizes[6];
    const int K     = in_sizes[7] / B;
    const int S     = K / 2 + 1;
    const int Ppool = in_sizes[8];
    const int Dout  = in_sizes[5];
    const int D     = in_sizes[4] / (2 * Dout);

    char* ws = (char*)d_ws;
    float* cat  = (float*)ws;                                   // B * 2D f32
    size_t cat_bytes = (size_t)B * 2 * D * sizeof(float);
    float* sv_g = (float*)(ws + cat_bytes);                     // Ppool f32
    int*   sg_g = (int*)(ws + cat_bytes + (size_t)Ppool * 4);   // Ppool i32

    sort_pool_kernel<<<(Ppool + 3) / 4, 256, 0, stream>>>(
        tp_logits, tp_idx, sv_g, sg_g, Ppool);

    row_kernel<<<B, 256, 0, stream>>>(
        features, all_logits, center_logits, center_idx, neighbor_idx,
        labels, avgp, sv_g, sg_g, cat, K, S, Ppool, D);

    gemm_relu_kernel<<<(B + 31) / 32, 256, 0, stream>>>(
        cat, W, bias, (float*)d_out, B, 2 * D);
}